// Round 3
// baseline (2196.740 us; speedup 1.0000x reference)
//
#include <hip/hip_runtime.h>
#include <math.h>

// ---------------------------------------------------------------------------
// CrossAttentionLayer_convk3s2 — FP32 inputs/outputs (reference is jnp.float32),
// bf16 MFMA internally (convert at LDS staging), fp32 accumulation.
// Folds: broadcast query -> per-(i,h) score vectors U/G (conv folded into G),
// attention linearity -> PV then single wv/cwv projection, biases folded.
// ---------------------------------------------------------------------------

typedef short   mfrag  __attribute__((ext_vector_type(8)));   // 8 x bf16 bits
typedef float   floatx4 __attribute__((ext_vector_type(4)));
typedef unsigned short us4 __attribute__((ext_vector_type(4)));
typedef unsigned int u32x4 __attribute__((ext_vector_type(4)));

#define LL   216     // 12*18 tokens
#define LC   54      // 6*9 coarse positions
#define TP1  136     // pitch (ushorts) for 128-col LDS rows (272B)
#define TP2  72      // pitch (ushorts) for 64-col LDS rows

__device__ __forceinline__ float b2f(unsigned short u){
  return __uint_as_float(((unsigned int)u) << 16);
}
__device__ __forceinline__ unsigned short f2b(float f){
  unsigned int x = __float_as_uint(f);
  return (unsigned short)((x + 0x7fffu + ((x >> 16) & 1u)) >> 16);
}
__device__ __forceinline__ floatx4 mfma16(mfrag a, mfrag b, floatx4 c){
  return __builtin_amdgcn_mfma_f32_16x16x32_bf16(a, b, c, 0, 0, 0);
}
__device__ __forceinline__ mfrag zfrag(){ mfrag z = {0,0,0,0,0,0,0,0}; return z; }

union F8 { unsigned short u[8]; mfrag v; };

struct Par {
  const float *query,*tgt,*ln1g,*ln1b,*ln2g,*ln2b,*wq,*bq,*wk,*wv,*bv,
              *wp,*bp,*f1w,*f1b,*f2w,*f2b,*cw,*cb;
  const float *ln1cg,*ln1cb,*ln2cg,*ln2cb,*wqc,*bqc,*wkc,*wvc,*bvc,
              *wpc,*bpc,*f1cw,*f1cb,*f2cw,*f2cb;
  unsigned short *U;      // [48][128] bf16: fine score vectors (0.25 * wk @ q_head)
  float          *uc;     // [32][128] f32: coarse score vectors pre-conv-fold
  float          *cvb;    // [128] f32: cb@wvc + bvc
  unsigned short *G;      // [9][32][128] bf16: cw_tap-folded coarse score vectors
  unsigned short *cwvT;   // [9][128 d][128 e] bf16: (cw_tap @ wvc) transposed
  unsigned short *wT;     // 6 x [128][128] bf16 transposed: wp,f1,f2,wpc,f1c,f2c
  float          *out;    // [4096*10][128] f32: att staged here, then final
};

// ------------------------------ K0a: tiny precompute (1 block) --------------
__global__ __launch_bounds__(256) void k0a(Par p){
  __shared__ float qn[10][128];
  __shared__ float qp[10][128];
  int tid = threadIdx.x;
  if (tid < 10){
    int r = tid;
    const float* row = p.query + r*128;
    float s1=0.f, s2=0.f;
    for (int c=0;c<128;c++){ float v=row[c]; s1+=v; s2+=v*v; }
    float m = s1/128.f, var = s2/128.f - m*m;
    float inv = rsqrtf(var + 1e-5f);
    const float* g  = (r<6)? p.ln1g : p.ln1cg;
    const float* bb = (r<6)? p.ln1b : p.ln1cb;
    for (int c=0;c<128;c++) qn[r][c] = (row[c]-m)*inv*g[c] + bb[c];
  }
  __syncthreads();
  for (int o=tid;o<1280;o+=256){
    int i=o>>7, d=o&127;
    const float* w  = (i<6)? p.wq : p.wqc;
    const float* bi = (i<6)? p.bq : p.bqc;
    float acc = bi[d];
    for (int c=0;c<128;c++) acc += qn[i][c]*w[c*128+d];
    qp[i][d]=acc;
  }
  __syncthreads();
  // fine score vectors u[ih][c] = 0.25 * sum_dd wk[c][h*16+dd]*q[i][h*16+dd]
  for (int o=tid;o<6144;o+=256){
    int ih=o>>7, c=o&127, i=ih>>3, h=ih&7;
    float a=0.f;
    for (int dd=0;dd<16;dd++) a += p.wk[c*128 + h*16+dd] * qp[i][h*16+dd];
    p.U[ih*128+c] = f2b(0.25f*a);
  }
  // coarse (pre-conv-fold), kept fp32 for K0b
  for (int o=tid;o<4096;o+=256){
    int ih=o>>7, c=o&127, i=ih>>3, h=ih&7;
    float a=0.f;
    for (int dd=0;dd<16;dd++) a += p.wkc[c*128 + h*16+dd] * qp[6+i][h*16+dd];
    p.uc[ih*128+c] = 0.25f*a;
  }
  if (tid < 128){
    int d = tid; float a = p.bvc[d];
    for (int c=0;c<128;c++) a += p.cb[c] * p.wvc[c*128+d];
    p.cvb[d] = a;
  }
}

// --------------------- K0b: folded weights (24 blocks) ----------------------
__global__ __launch_bounds__(256) void k0b(Par p){
  int bid = blockIdx.x, tid = threadIdx.x;
  if (bid < 9){            // G[tap][ih][e] = sum_c cw[tap][e][c]*uc[ih][c]
    int tap = bid;
    for (int o=tid;o<4096;o+=256){
      int ih=o>>7, e=o&127; float a=0.f;
      const float* cwr = p.cw + (tap*128+e)*128;
      const float* ucr = p.uc + ih*128;
      for (int c=0;c<128;c++) a += cwr[c]*ucr[c];
      p.G[(tap*32+ih)*128 + e] = f2b(a);
    }
  } else if (bid < 18){    // cwvT[tap][d][e] = sum_c cw[tap][e][c]*wvc[c][d]
    int tap = bid-9;
    for (int o=tid;o<16384;o+=256){
      int d=o>>7, e=o&127; float a=0.f;
      const float* cwr = p.cw + (tap*128+e)*128;
      for (int c=0;c<128;c++) a += cwr[c]*p.wvc[c*128+d];
      p.cwvT[(tap*128+d)*128 + e] = f2b(a);
    }
  } else {                 // transposed FFN weights (f32 -> bf16)
    int j = bid-18;
    const float* src;
    switch(j){ case 0: src=p.wp;  break; case 1: src=p.f1w;  break;
               case 2: src=p.f2w; break; case 3: src=p.wpc;  break;
               case 4: src=p.f1cw;break; default: src=p.f2cw; }
    unsigned short* dst = p.wT + j*16384;
    for (int o=tid;o<16384;o+=256){ int n=o>>7,k=o&127; dst[o] = f2b(src[k*128+n]); }
  }
}

// staging helper: f32 global row -> bf16 LDS row (zero for pad/invalid)
__device__ __forceinline__ void stage_coarse(unsigned short* ts,
                                             const float* tb,
                                             int tap, int tid){
  int dy = tap/3, dx = tap%3;
  for (int ci=tid; ci<64*32; ci+=256){
    int row = ci>>5, c4 = ci&31;
    float4 v = make_float4(0.f,0.f,0.f,0.f);
    if (row < LC){
      int ip = row/9, jp = row - ip*9;
      int r = ip*2 + dy - 1, c = jp*2 + dx - 1;
      if (r>=0 && r<12 && c>=0 && c<18)
        v = *reinterpret_cast<const float4*>(tb + (r*18+c)*128 + c4*4);
    }
    us4 o = { f2b(v.x), f2b(v.y), f2b(v.z), f2b(v.w) };
    *reinterpret_cast<us4*>(ts + row*TP1 + c4*4) = o;
  }
}

// ------------------------------ MAIN: one batch per block -------------------
__global__ __launch_bounds__(256) void kmain(Par p){
  __shared__ alignas(16) unsigned short ts[64*TP1];   // staged T rows (bf16)
  __shared__ alignas(16) unsigned short gs[32*TP1];   // staged G tap
  __shared__ float sf[36*9];                          // fine scores [l][h]
  __shared__ float sct[54*33];                        // coarse scores [l][ih]
  __shared__ alignas(16) unsigned short aw[8*TP2];    // fine softmax weights [h][l]
  __shared__ alignas(16) unsigned short ac[32*TP2];   // coarse masked weights [ih][l]
  __shared__ float rb[8*129];                         // fine PV result [h][c]
  __shared__ alignas(16) unsigned short rt[32*TP1];   // coarse per-tap wsum [ih][e]
  __shared__ float ob[128];

  int tid = threadIdx.x;
  int b   = blockIdx.x;
  int lane = tid & 63, wvx = tid >> 6;
  int q4 = lane >> 4, n16 = lane & 15;
  const float* tb = p.tgt + (size_t)b*LL*128;

  // ======================= FINE: 6 windows of 6x6 ===========================
  for (int win=0; win<6; win++){
    int r0 = (win/3)*6, c0 = (win%3)*6;
    for (int ci=tid; ci<64*32; ci+=256){
      int row=ci>>5, c4=ci&31;
      float4 v = make_float4(0.f,0.f,0.f,0.f);
      if (row<36){
        int grow = (r0 + row/6)*18 + c0 + row%6;
        v = *reinterpret_cast<const float4*>(tb + grow*128 + c4*4);
      }
      us4 o = { f2b(v.x), f2b(v.y), f2b(v.z), f2b(v.w) };
      *reinterpret_cast<us4*>(ts + row*TP1 + c4*4) = o;
    }
    __syncthreads();
    // F1: scores S^T[l][h] = sum_d T[l][d] * U[win*8+h][d]
    if (wvx < 3){
      floatx4 acc = {0.f,0.f,0.f,0.f};
      #pragma unroll
      for (int ks=0; ks<4; ks++){
        mfrag a = *reinterpret_cast<const mfrag*>(ts + (wvx*16+n16)*TP1 + ks*32 + q4*8);
        mfrag bf = zfrag();
        if (n16 < 8) bf = *reinterpret_cast<const mfrag*>(p.U + (win*8+n16)*128 + ks*32 + q4*8);
        acc = mfma16(a, bf, acc);
      }
      if (n16 < 8){
        #pragma unroll
        for (int r=0;r<4;r++){
          int l = wvx*16 + q4*4 + r;
          if (l < 36) sf[l*9 + n16] = acc[r];
        }
      }
    }
    __syncthreads();
    // F2: softmax over 36 tokens per head
    if (tid < 8){
      float mx = -1e30f;
      for (int l=0;l<36;l++) mx = fmaxf(mx, sf[l*9+tid]);
      float sm=0.f;
      for (int l=0;l<36;l++){ float e=__expf(sf[l*9+tid]-mx); sm+=e; sf[l*9+tid]=e; }
      float inv = 1.f/sm;
      for (int l=0;l<64;l++)
        aw[tid*TP2 + l] = (l<36)? f2b(sf[l*9+tid]*inv) : (unsigned short)0;
    }
    __syncthreads();
    // F3: PV  r[h][d] = sum_l a[h][l] * T[l][d]
    #pragma unroll
    for (int t2=0;t2<2;t2++){
      int nt = wvx*2 + t2;
      floatx4 acc={0.f,0.f,0.f,0.f};
      #pragma unroll
      for (int ks=0;ks<2;ks++){
        mfrag a = zfrag();
        if (n16 < 8) a = *reinterpret_cast<const mfrag*>(aw + n16*TP2 + ks*32 + q4*8);
        F8 bb;
        #pragma unroll
        for (int j=0;j<8;j++)
          bb.u[j] = ts[(ks*32 + q4*8 + j)*TP1 + nt*16 + n16];
        acc = mfma16(a, bb.v, acc);
      }
      #pragma unroll
      for (int r=0;r<4;r++){
        int h = q4*4 + r;
        if (h < 8) rb[h*129 + nt*16 + n16] = acc[r];
      }
    }
    __syncthreads();
    // F4: out[d] = sum_c r[h(d)][c]*wv[c][d] + bv[d]  -> staged into d_out (f32)
    {
      int d = tid & 127, half = tid >> 7, h = d >> 4;
      float ppp = 0.f;
      for (int c=half*64; c<half*64+64; c++) ppp += rb[h*129+c] * p.wv[c*128+d];
      if (half==0) ob[d] = ppp;
      __syncthreads();
      if (half==1)
        p.out[((size_t)b*10+win)*128 + d] = ob[d] + ppp + p.bv[d];
    }
    __syncthreads();
  }

  // =================== COARSE scores: 9 taps, acc in regs ===================
  floatx4 facc0={0.f,0.f,0.f,0.f}, facc1={0.f,0.f,0.f,0.f};
  for (int tap=0;tap<9;tap++){
    __syncthreads();
    stage_coarse(ts, tb, tap, tid);
    for (int ci=tid; ci<32*16; ci+=256){
      int row=ci>>4, c16=ci&15;
      *reinterpret_cast<u32x4*>(gs + row*TP1 + c16*8) =
        *reinterpret_cast<const u32x4*>(p.G + (tap*32+row)*128 + c16*8);
    }
    __syncthreads();
    mfrag A0 = *reinterpret_cast<const mfrag*>(ts + (wvx*16+n16)*TP1 + 0*32 + q4*8);
    mfrag A1 = *reinterpret_cast<const mfrag*>(ts + (wvx*16+n16)*TP1 + 1*32 + q4*8);
    mfrag A2 = *reinterpret_cast<const mfrag*>(ts + (wvx*16+n16)*TP1 + 2*32 + q4*8);
    mfrag A3 = *reinterpret_cast<const mfrag*>(ts + (wvx*16+n16)*TP1 + 3*32 + q4*8);
    #pragma unroll
    for (int nt=0;nt<2;nt++){
      floatx4 fa = nt? facc1 : facc0;
      mfrag B0 = *reinterpret_cast<const mfrag*>(gs + (nt*16+n16)*TP1 + 0*32 + q4*8);
      mfrag B1 = *reinterpret_cast<const mfrag*>(gs + (nt*16+n16)*TP1 + 1*32 + q4*8);
      mfrag B2 = *reinterpret_cast<const mfrag*>(gs + (nt*16+n16)*TP1 + 2*32 + q4*8);
      mfrag B3 = *reinterpret_cast<const mfrag*>(gs + (nt*16+n16)*TP1 + 3*32 + q4*8);
      fa = mfma16(A0,B0,fa); fa = mfma16(A1,B1,fa);
      fa = mfma16(A2,B2,fa); fa = mfma16(A3,B3,fa);
      if (nt) facc1 = fa; else facc0 = fa;
    }
  }
  #pragma unroll
  for (int nt=0;nt<2;nt++){
    floatx4 fa = nt? facc1 : facc0;
    #pragma unroll
    for (int r=0;r<4;r++){
      int l = wvx*16 + q4*4 + r;
      if (l < LC) sct[l*33 + nt*16 + n16] = fa[r];
    }
  }
  __syncthreads();
  // C2: softmax per (i,h) over its window (masked full-K weights into ac)
  if (tid < 32){
    int i = tid>>3;
    int rA = (i>>1)*3, cA = (i&1)*4, cB = (i&1)? 9 : 4;
    float mx = -1e30f;
    for (int r=rA;r<rA+3;r++) for (int c=cA;c<cB;c++)
      mx = fmaxf(mx, sct[(r*9+c)*33 + tid]);
    float sm=0.f;
    for (int r=rA;r<rA+3;r++) for (int c=cA;c<cB;c++){
      int l=r*9+c; float e=__expf(sct[l*33+tid]-mx); sm+=e; sct[l*33+tid]=e;
    }
    float inv=1.f/sm;
    for (int l=0;l<64;l++){
      unsigned short v = 0;
      if (l < LC){
        int r = l/9, c = l - r*9;
        if (r>=rA && r<rA+3 && c>=cA && c<cB) v = f2b(sct[l*33+tid]*inv);
      }
      ac[tid*TP2 + l] = v;
    }
  }
  __syncthreads();
  // C3: per tap: rt[ih][e] = sum_l a[ih][l] T_tap[l][e]; project by cwvT,
  //     accumulate out_c[i][d] across taps in registers.
  floatx4 pacc0={0.f,0.f,0.f,0.f}, pacc1={0.f,0.f,0.f,0.f};
  for (int tap=0;tap<9;tap++){
    __syncthreads();
    stage_coarse(ts, tb, tap, tid);
    __syncthreads();
    #pragma unroll
    for (int t2=0;t2<2;t2++){
      int nt = wvx*2+t2;
      F8 B0, B1;
      #pragma unroll
      for (int j=0;j<8;j++){
        B0.u[j] = ts[(q4*8+j)*TP1      + nt*16+n16];
        B1.u[j] = ts[(32+q4*8+j)*TP1   + nt*16+n16];
      }
      #pragma unroll
      for (int mt=0;mt<2;mt++){
        mfrag a0 = *reinterpret_cast<const mfrag*>(ac + (mt*16+n16)*TP2 + 0*32 + q4*8);
        mfrag a1 = *reinterpret_cast<const mfrag*>(ac + (mt*16+n16)*TP2 + 1*32 + q4*8);
        floatx4 rr = {0.f,0.f,0.f,0.f};
        rr = mfma16(a0, B0.v, rr);
        rr = mfma16(a1, B1.v, rr);
        #pragma unroll
        for (int r=0;r<4;r++){
          int ih = mt*16 + q4*4 + r;
          rt[ih*TP1 + nt*16+n16] = f2b(rr[r]);
        }
      }
    }
    __syncthreads();
    #pragma unroll
    for (int hh=0;hh<2;hh++){
      int h = wvx*2+hh;
      floatx4 pa = hh? pacc1 : pacc0;
      #pragma unroll
      for (int ks=0;ks<4;ks++){
        mfrag a = zfrag();
        if (n16 < 4) a = *reinterpret_cast<const mfrag*>(rt + (n16*8+h)*TP1 + ks*32 + q4*8);
        mfrag bbb = *reinterpret_cast<const mfrag*>(p.cwvT + ((size_t)tap*128 + h*16 + n16)*128 + ks*32 + q4*8);
        pa = mfma16(a, bbb, pa);
      }
      if (hh) pacc1 = pa; else pacc0 = pa;
    }
  }
  if (q4 == 0){
    #pragma unroll
    for (int hh=0;hh<2;hh++){
      int h = wvx*2+hh;
      floatx4 pa = hh? pacc1 : pacc0;
      #pragma unroll
      for (int r=0;r<4;r++){
        int d = h*16 + n16;
        p.out[((size_t)b*10 + 6 + r)*128 + d] = pa[r] + p.cvb[d];
      }
    }
  }
}

// ------------------- K2: proj + residual + LN + GELU FFN --------------------
// Reads 64 att rows (f32) from d_out, writes final values back to same rows.
__global__ __launch_bounds__(256) void kffn(Par p){
  __shared__ alignas(16) unsigned short ba[64*TP1];   // bf16 work buffer
  __shared__ alignas(16) unsigned short bbq[64*TP1];  // bf16 work buffer
  __shared__ alignas(16) unsigned short xb[64*TP1];   // bf16 pre-LN residual x
  int tid=threadIdx.x, bid=blockIdx.x;
  int lane=tid&63, wvv=tid>>6, q4=lane>>4, n16=lane&15;
  bool fine = bid < 384;
  int rows0 = fine? bid*64 : (bid-384)*64;
  int TPB = fine? 6 : 4, toff = fine? 0 : 6;
  const unsigned short* w1 = p.wT + (fine?0:3)*16384;
  const unsigned short* w2 = p.wT + (fine?1:4)*16384;
  const unsigned short* w3 = p.wT + (fine?2:5)*16384;
  const float* bi1 = fine? p.bp  : p.bpc;
  const float* bi2 = fine? p.f1b : p.f1cb;
  const float* bi3 = fine? p.f2b : p.f2cb;
  const float* g2  = fine? p.ln2g : p.ln2cg;
  const float* be2 = fine? p.ln2b : p.ln2cb;

  for (int ci=tid; ci<64*32; ci+=256){
    int row=ci>>5, c4=ci&31;
    int grow = rows0 + row;
    int bglob = grow / TPB, t = toff + (grow % TPB);
    float4 v = *reinterpret_cast<const float4*>(p.out + ((size_t)bglob*10+t)*128 + c4*4);
    us4 o = { f2b(v.x), f2b(v.y), f2b(v.z), f2b(v.w) };
    *reinterpret_cast<us4*>(ba + row*TP1 + c4*4) = o;
  }
  __syncthreads();
  { // x = sc + att@wp + bp   (store x as bf16 in xb)
    mfrag A[4];
    #pragma unroll
    for (int ks=0;ks<4;ks++) A[ks] = *reinterpret_cast<const mfrag*>(ba + (wvv*16+n16)*TP1 + ks*32+q4*8);
    for (int nt=0;nt<8;nt++){
      floatx4 acc={0.f,0.f,0.f,0.f};
      #pragma unroll
      for (int ks=0;ks<4;ks++){
        mfrag Bf = *reinterpret_cast<const mfrag*>(w1 + (nt*16+n16)*128 + ks*32+q4*8);
        acc = mfma16(A[ks], Bf, acc);
      }
      #pragma unroll
      for (int r=0;r<4;r++){
        int row = wvv*16+q4*4+r;
        int grow = rows0 + row;
        int t = toff + (grow % TPB);
        int d = nt*16+n16;
        xb[row*TP1+d] = f2b(acc[r] + bi1[d] + p.query[t*128+d]);
      }
    }
  }
  __syncthreads();
  if (tid < 64){ // LayerNorm over x
    int row=tid; float s1=0.f,s2=0.f;
    for (int c=0;c<128;c++){ float v=b2f(xb[row*TP1+c]); s1+=v; s2+=v*v; }
    float m=s1/128.f, var=s2/128.f-m*m, inv=rsqrtf(var+1e-5f);
    for (int c=0;c<128;c++){
      float v=(b2f(xb[row*TP1+c])-m)*inv*g2[c]+be2[c];
      bbq[row*TP1+c]=f2b(v);
    }
  }
  __syncthreads();
  { // h = gelu(xn@f1 + b1)
    mfrag A[4];
    #pragma unroll
    for (int ks=0;ks<4;ks++) A[ks] = *reinterpret_cast<const mfrag*>(bbq + (wvv*16+n16)*TP1 + ks*32+q4*8);
    for (int nt=0;nt<8;nt++){
      floatx4 acc={0.f,0.f,0.f,0.f};
      #pragma unroll
      for (int ks=0;ks<4;ks++){
        mfrag Bf = *reinterpret_cast<const mfrag*>(w2 + (nt*16+n16)*128 + ks*32+q4*8);
        acc = mfma16(A[ks], Bf, acc);
      }
      #pragma unroll
      for (int r=0;r<4;r++){
        int row=wvv*16+q4*4+r, d=nt*16+n16;
        float v = acc[r] + bi2[d];
        ba[row*TP1+d] = f2b(0.5f*v*(1.f+erff(v*0.70710678118f)));
      }
    }
  }
  __syncthreads();
  { // out = x + h@f2 + b2   (f32 out)
    mfrag A[4];
    #pragma unroll
    for (int ks=0;ks<4;ks++) A[ks] = *reinterpret_cast<const mfrag*>(ba + (wvv*16+n16)*TP1 + ks*32+q4*8);
    for (int nt=0;nt<8;nt++){
      floatx4 acc={0.f,0.f,0.f,0.f};
      #pragma unroll
      for (int ks=0;ks<4;ks++){
        mfrag Bf = *reinterpret_cast<const mfrag*>(w3 + (nt*16+n16)*128 + ks*32+q4*8);
        acc = mfma16(A[ks], Bf, acc);
      }
      #pragma unroll
      for (int r=0;r<4;r++){
        int row=wvv*16+q4*4+r, d=nt*16+n16;
        int grow=rows0+row;
        int bglob = grow / TPB, t = toff + (grow % TPB);
        p.out[((size_t)bglob*10+t)*128+d] = b2f(xb[row*TP1+d]) + acc[r] + bi3[d];
      }
    }
  }
}

// ---------------------------------------------------------------------------
extern "C" void kernel_launch(void* const* d_in, const int* in_sizes, int n_in,
                              void* d_out, int out_size, void* d_ws, size_t ws_size,
                              hipStream_t stream){
  (void)in_sizes; (void)n_in; (void)out_size; (void)ws_size;
  Par p;
  p.query=(const float*)d_in[0];  p.tgt  =(const float*)d_in[1];
  p.ln1g =(const float*)d_in[2];  p.ln1b =(const float*)d_in[3];
  p.ln2g =(const float*)d_in[4];  p.ln2b =(const float*)d_in[5];
  p.wq   =(const float*)d_in[6];  p.bq   =(const float*)d_in[7];
  p.wk   =(const float*)d_in[8];  /* bk d_in[9] unused (softmax-invariant) */
  p.wv   =(const float*)d_in[10]; p.bv   =(const float*)d_in[11];
  p.wp   =(const float*)d_in[12]; p.bp   =(const float*)d_in[13];
  p.f1w  =(const float*)d_in[14]; p.f1b  =(const float*)d_in[15];
  p.f2w  =(const float*)d_in[16]; p.f2b  =(const float*)d_in[17];
  p.cw   =(const float*)d_in[18]; p.cb   =(const float*)d_in[19];
  p.ln1cg=(const float*)d_in[20]; p.ln1cb=(const float*)d_in[21];
  p.ln2cg=(const float*)d_in[22]; p.ln2cb=(const float*)d_in[23];
  p.wqc  =(const float*)d_in[24]; p.bqc  =(const float*)d_in[25];
  p.wkc  =(const float*)d_in[26]; /* bkc d_in[27] unused */
  p.wvc  =(const float*)d_in[28]; p.bvc  =(const float*)d_in[29];
  p.wpc  =(const float*)d_in[30]; p.bpc  =(const float*)d_in[31];
  p.f1cw =(const float*)d_in[32]; p.f1cb =(const float*)d_in[33];
  p.f2cw =(const float*)d_in[34]; p.f2cb =(const float*)d_in[35];
  char* ws = (char*)d_ws;
  p.U    = (unsigned short*)(ws + 0);        //  12,288 B
  p.uc   = (float*)        (ws + 16384);     //  16,384 B
  p.cvb  = (float*)        (ws + 49152);     //     512 B
  p.G    = (unsigned short*)(ws + 65536);    //  73,728 B
  p.cwvT = (unsigned short*)(ws + 147456);   // 294,912 B
  p.wT   = (unsigned short*)(ws + 458752);   // 196,608 B  (ends ~640 KB)
  p.out  = (float*)d_out;

  k0a <<<dim3(1),    dim3(256), 0, stream>>>(p);
  k0b <<<dim3(24),   dim3(256), 0, stream>>>(p);
  kmain<<<dim3(4096), dim3(256), 0, stream>>>(p);
  kffn <<<dim3(640),  dim3(256), 0, stream>>>(p);
}